// Round 3
// baseline (96.768 us; speedup 1.0000x reference)
//
#include <hip/hip_runtime.h>

// out[b,n] = sum_m exp(-||qp[b,n,:2]-sp[b,m,:2]||) * f[b,m] / sum_m exp(-...)
// Shapes: qp [4,4096,3], sp [4,8192,3], feats [4,8192,1], out [4,4096,1] fp32.
//
// R3: LDS-pipe was the R2 bottleneck (1 ds_read_b128 per point per wave = 12cyc
// serving only 64 pairs -> 41us floor). Now each thread owns 4 queries (QPT=4),
// so one staged point feeds 4 pair-updates; LDS pipe load drops 4x and VALU
// becomes the limit (~26 cyc / wave-pair, ~22us). Dot+accum written as float2
// over query pairs to coax v_pk_fma_f32 (packed fp32) from the backend.

#define B_DIM   4
#define N_DIM   4096
#define M_DIM   8192
#define NQ      (B_DIM * N_DIM)     // 16384
#define THREADS 256
#define QPT     4                   // queries per thread
#define QPB     (THREADS * QPT)     // 1024 queries per block
#define QGROUPS (NQ / QPB)          // 16
#define SPLITS  32                  // M splits (blockIdx.y)
#define CHUNK   (M_DIM / SPLITS)    // 256 scene points per block (== THREADS)

typedef float v2f __attribute__((ext_vector_type(2)));

__global__ __launch_bounds__(THREADS) void mfe_main(
    const float* __restrict__ qp,     // [B,N,3]
    const float* __restrict__ sp,     // [B,M,3]
    const float* __restrict__ feats,  // [B,M,1]
    float* __restrict__ psw,          // [SPLITS][NQ] or [NQ] (atomic)
    float* __restrict__ pswf,         // same
    int use_atomic)
{
    __shared__ float4 pts[CHUNK];          // {x, y, L2*(x^2+y^2), f} : 4 KB

    const float L2 = 2.0813689810056077f;  // (log2 e)^2

    const int tid  = threadIdx.x;
    const int qg   = blockIdx.x;           // 0..QGROUPS-1
    const int s    = blockIdx.y;           // 0..SPLITS-1
    const int lane = tid & 63;
    const int w    = tid >> 6;
    const int qbase = qg * QPB + w * (QPT * 64) + lane;  // +k*64, k=0..3
    const int b     = qg / (N_DIM / QPB);  // batch (uniform per block)

    // Stage this block's 256-point chunk (1 point per thread).
    {
        const int m = b * M_DIM + s * CHUNK + tid;
        const float x = sp[m * 3 + 0];
        const float y = sp[m * 3 + 1];
        const float f = feats[m];
        pts[tid] = make_float4(x, y, L2 * fmaf(x, x, y * y), f);
    }

    // Per-query constants: d2*L2 = ca*x + cb*y + X2 + Q2
    float qx[QPT], qy[QPT];
    #pragma unroll
    for (int k = 0; k < QPT; ++k) {
        const int q = qbase + k * 64;
        qx[k] = qp[q * 3 + 0];
        qy[k] = qp[q * 3 + 1];
    }
    const v2f caA = { -2.0f * L2 * qx[0], -2.0f * L2 * qx[1] };
    const v2f caB = { -2.0f * L2 * qx[2], -2.0f * L2 * qx[3] };
    const v2f cbA = { -2.0f * L2 * qy[0], -2.0f * L2 * qy[1] };
    const v2f cbB = { -2.0f * L2 * qy[2], -2.0f * L2 * qy[3] };
    const v2f q2A = { L2 * fmaf(qx[0], qx[0], qy[0] * qy[0]),
                      L2 * fmaf(qx[1], qx[1], qy[1] * qy[1]) };
    const v2f q2B = { L2 * fmaf(qx[2], qx[2], qy[2] * qy[2]),
                      L2 * fmaf(qx[3], qx[3], qy[3] * qy[3]) };

    v2f swA  = {0.f, 0.f}, swB  = {0.f, 0.f};
    v2f swfA = {0.f, 0.f}, swfB = {0.f, 0.f};

    __syncthreads();

    #pragma unroll 4
    for (int j = 0; j < CHUNK; ++j) {
        const float4 P = pts[j];           // wave-uniform addr -> broadcast
        const v2f px = { P.x, P.x };
        const v2f py = { P.y, P.y };
        const v2f pz = { P.z, P.z };
        const v2f pf = { P.w, P.w };

        v2f tA = __builtin_elementwise_fma(caA, px, q2A);
        v2f tB = __builtin_elementwise_fma(caB, px, q2B);
        tA = __builtin_elementwise_fma(cbA, py, tA);
        tB = __builtin_elementwise_fma(cbB, py, tB);
        tA = tA + pz;
        tB = tB + pz;

        v2f wva, wvb;
        wva.x = __builtin_amdgcn_exp2f(-__builtin_amdgcn_sqrtf(fabsf(tA.x)));
        wva.y = __builtin_amdgcn_exp2f(-__builtin_amdgcn_sqrtf(fabsf(tA.y)));
        wvb.x = __builtin_amdgcn_exp2f(-__builtin_amdgcn_sqrtf(fabsf(tB.x)));
        wvb.y = __builtin_amdgcn_exp2f(-__builtin_amdgcn_sqrtf(fabsf(tB.y)));

        swA += wva;
        swB += wvb;
        swfA = __builtin_elementwise_fma(wva, pf, swfA);
        swfB = __builtin_elementwise_fma(wvb, pf, swfB);
    }

    const float sw_k[QPT]  = { swA.x,  swA.y,  swB.x,  swB.y  };
    const float swf_k[QPT] = { swfA.x, swfA.y, swfB.x, swfB.y };

    if (!use_atomic) {
        #pragma unroll
        for (int k = 0; k < QPT; ++k) {
            const int q = qbase + k * 64;
            psw [s * NQ + q] = sw_k[k];    // coalesced per wave
            pswf[s * NQ + q] = swf_k[k];
        }
    } else {
        #pragma unroll
        for (int k = 0; k < QPT; ++k) {
            const int q = qbase + k * 64;
            atomicAdd(&psw[q],  sw_k[k]);
            atomicAdd(&pswf[q], swf_k[k]);
        }
    }
}

__global__ __launch_bounds__(256) void mfe_div(
    const float* __restrict__ psw,
    const float* __restrict__ pswf,
    float* __restrict__ out, int nsum)
{
    const int i = blockIdx.x * 256 + threadIdx.x;
    float sw = 0.f, swf = 0.f;
    for (int s = 0; s < nsum; ++s) {
        sw  += psw [s * NQ + i];
        swf += pswf[s * NQ + i];
    }
    out[i] = swf / sw;
}

extern "C" void kernel_launch(void* const* d_in, const int* in_sizes, int n_in,
                              void* d_out, int out_size, void* d_ws, size_t ws_size,
                              hipStream_t stream) {
    const float* qp    = (const float*)d_in[0];
    const float* sp    = (const float*)d_in[1];
    const float* feats = (const float*)d_in[2];
    float* out = (float*)d_out;

    const size_t need = (size_t)2 * SPLITS * NQ * sizeof(float);  // 4 MB
    dim3 grid(QGROUPS, SPLITS);

    if (ws_size >= need) {
        float* psw  = (float*)d_ws;
        float* pswf = psw + (size_t)SPLITS * NQ;
        mfe_main<<<grid, THREADS, 0, stream>>>(qp, sp, feats, psw, pswf, 0);
        mfe_div<<<NQ / 256, 256, 0, stream>>>(psw, pswf, out, SPLITS);
    } else {
        float* psw  = (float*)d_ws;       // [NQ]
        float* pswf = psw + NQ;
        hipMemsetAsync(d_ws, 0, 2 * NQ * sizeof(float), stream);
        mfe_main<<<grid, THREADS, 0, stream>>>(qp, sp, feats, psw, pswf, 1);
        mfe_div<<<NQ / 256, 256, 0, stream>>>(psw, pswf, out, 1);
    }
}